// Round 12
// baseline (374.651 us; speedup 1.0000x reference)
//
#include <hip/hip_runtime.h>
#include <stdint.h>

#define TT 512
#define BB 32
#define EE 512
#define HH 2048

typedef __attribute__((ext_vector_type(8))) short short8;   // 8 x bf16 (4 VGPRs)
typedef __attribute__((ext_vector_type(4))) float f32x4;    // MFMA accumulator

// LDS geometry (in shorts)
#define XROW 528            // 512 data + 16 pad: measured 0 bank conflicts;
                            // 520 gave 8.4M conflicts. Row stride 1056 B.
#define XBUF (16 * XROW)    // one 16-t chunk buffer = 8448 shorts (16.5 KB)

static __device__ __forceinline__ float fast_exp(float x) {
    return __builtin_amdgcn_exp2f(x * 1.44269504f);
}
static __device__ __forceinline__ float fast_rcp(float x) {
    return __builtin_amdgcn_rcpf(x);
}

// Packed fp32->bf16 RNE convert: 1 instr per 2 elements.
static __device__ __forceinline__ unsigned cvtpk_bf16(float lo, float hi) {
    unsigned r;
    asm("v_cvt_pk_bf16_f32 %0, %1, %2" : "=v"(r) : "v"(lo), "v"(hi));
    return r;
}

// Async global->LDS DMA, 16 B/lane (wave-uniform LDS base + lane*16).
static __device__ __forceinline__ void load_lds16(const unsigned short* g, unsigned short* l) {
    __builtin_amdgcn_global_load_lds(
        (const __attribute__((address_space(1))) unsigned int*)(uintptr_t)g,
        (__attribute__((address_space(3))) unsigned int*)(uintptr_t)l,
        16, 0, 0);
}

// ---------------------------------------------------------------------------
// Pre-kernel (R9-verified): BW-optimal convert.
// ---------------------------------------------------------------------------
__launch_bounds__(256, 8)
__global__ void convert_inputs(const float* __restrict__ X,
                               const float* __restrict__ W,
                               unsigned short* __restrict__ Xb,
                               unsigned short* __restrict__ Wb) {
    const int bid = blockIdx.x;
    const float* src;
    unsigned short* dst;
    size_t base;
    if (bid < 2048) { src = X; dst = Xb; base = (size_t)bid * 4096; }
    else            { src = W; dst = Wb; base = (size_t)(bid - 2048) * 4096; }
    size_t j = base + (size_t)threadIdx.x * 16;

    float4 v0 = *(const float4*)(src + j);
    float4 v1 = *(const float4*)(src + j + 4);
    float4 v2 = *(const float4*)(src + j + 8);
    float4 v3 = *(const float4*)(src + j + 12);
    union { short8 s; unsigned u[4]; } o0, o1;
    o0.u[0] = cvtpk_bf16(v0.x, v0.y);
    o0.u[1] = cvtpk_bf16(v0.z, v0.w);
    o0.u[2] = cvtpk_bf16(v1.x, v1.y);
    o0.u[3] = cvtpk_bf16(v1.z, v1.w);
    o1.u[0] = cvtpk_bf16(v2.x, v2.y);
    o1.u[1] = cvtpk_bf16(v2.z, v2.w);
    o1.u[2] = cvtpk_bf16(v3.x, v3.y);
    o1.u[3] = cvtpk_bf16(v3.z, v3.w);
    *(short8*)(dst + j)     = o0.s;
    *(short8*)(dst + j + 8) = o1.s;
}

// ---------------------------------------------------------------------------
// Fused QRNN kernel — R15: HIERARCHICAL SCAN (the serial structure removed).
//
// The affine recurrence composes associatively; two-level scan:
//  L1 (parallel): each chunk's local scan with entry=0, tracking per-t
//     (oA_t, oM_t) pairs in registers and the chunk composition (Ac, Mc).
//  L2 (tiny serial): 32-step FMA chain over (Ac,Mc) gives every chunk's
//     entry carry.
//  L3 (parallel): vmax = max_t(oA_t + oM_t * entry[chunk]).
// The 32 barrier-spaced serial regions of all prior variants become ~20
// uniform barriers with only a ~400-cyc serial combine.
//
// Block: 512 thr = 2 t-halves (th) x {z,f,o,scan} roles.
//  - gate wave (role 0..2): R10-verified form — 1 gate, 16 h, full K=512,
//    W = 16 frags pinned in 64 AGPR; per region 16 A-reads + 16 MFMA
//    (2 chains) + one f32x4 publish to exch[buf][th] ([64][12], verified).
//  - scan wave (role 3): per region, act(chunk ch-1) + LOCAL scan (entry=0)
//    + store pairs (static idx via full unroll) + write (Ac,Mc) summary.
//    NO cross-region dependency -> no straggler chain.
//  - X staged per t-half by its 4 waves (verified DMA/XROW geometry),
//    double-buffered; chunk ch in region ch.
// Epilogue: B17; wv0 lanes 0..15 preload 32 summaries + 32-FMA serial chain
// -> entry[]; B18; scan waves apply pairs + q-reduce -> rmax[th]; B19; wv0
// writes out = max(rmax[0], rmax[1]).
//
// Barrier pairing: both role paths execute exactly 20 __syncthreads
// (B0 + 16 region + B17 + B18 + B19); all wave-uniform.
// Hazards: (1) publish(ch) vs scan read(ch) in region ch+1: barrier(ch).
// (2) scan reads slot (ch-1)&1 in region ch vs republish region ch+1:
// reads drained (lgkm) at barrier(ch). (3) X dbuf WAR/RAW: verified R1
// pattern (stage ch+1 in region ch; vmcnt+lgkm drained at each barrier).
// (4) summ written region ch (lanes 48-63) read after B17. (5) entry
// written by wv0, read after B18. (6) rmax written before B19, read after.
// ---------------------------------------------------------------------------
__launch_bounds__(512, 2)
__global__ void qrnn_fused(const unsigned short* __restrict__ Xb, // bf16 (T,B,E)
                           const unsigned short* __restrict__ Wb, // bf16 (3H,E)
                           const float* __restrict__ bias,        // (3H)
                           float* __restrict__ out)               // (B,H) fp32
{
    __shared__ unsigned short xlds[4 * XBUF];   // [th][buf] 67,584 B
    __shared__ float exch[2][2][64][12];        // [buf][th][lane][12] 12,288 B
    __shared__ float summ[32][16][2];           // (Ac,Mc) per (chunk,h) 4,096 B
    __shared__ float entry[32][16];             // chunk entry carries 2,048 B
    __shared__ float rmax[2][16];               // per-th partial max 128 B
                                                // total 86,144 B -> 1 block/CU

    const int tid  = threadIdx.x;
    const int wv   = tid >> 6;         // wave 0..7
    const int lane = tid & 63;
    const int q    = lane >> 4;        // quad 0..3
    const int c    = lane & 15;        // h-col (and A m-row) within tile
    const int th   = wv >> 2;          // t-half 0..1 (256 t each)
    const int role = wv & 3;           // 0..2 = gate z/f/o, 3 = scan

    // XCD-aware swizzle: 4096 blocks = 8 XCDs x 4 batches x 128 h-groups.
    const int id   = blockIdx.x;
    const int xcd  = id & 7;
    const int slot = id >> 3;
    const int b    = xcd * 4 + (slot >> 7);
    const int hgrp = slot & 127;
    const int h    = hgrp * 16 + c;

    // ---- staging: wave stages rows role*4..role*4+3 of its th's chunk ----
    const unsigned short* g0 =
        Xb + ((size_t)(th * 256 + role * 4) * BB + b) * EE + lane * 8;
    unsigned short* l0 = &xlds[th * 2 * XBUF] + role * 4 * XROW;

    auto stage = [&](int n, int buf) {
        const unsigned short* g = g0 + (size_t)n * 16 * BB * EE;
        unsigned short* l = l0 + buf * XBUF;
#pragma unroll
        for (int i = 0; i < 4; ++i)
            load_lds16(g + (size_t)i * (BB * EE), l + i * XROW);
    };

    if (role < 3) {
        // ================= GATE WAVE (R10-verified form) =================
        short8 wg[16];
        {
            const unsigned short* wr = Wb + ((size_t)role * HH + h) * EE;
#pragma unroll
            for (int k = 0; k < 16; ++k)
                wg[k] = *(const short8*)(wr + k * 32 + q * 8);
#pragma unroll
            for (int k = 0; k < 16; ++k)
                asm volatile("" : "+a"(wg[k]));
        }

        stage(0, 0);
        __syncthreads();                                   // B0

        for (int ch = 0; ch < 16; ++ch) {
            const int buf = ch & 1;
            if (ch < 15) stage(ch + 1, buf ^ 1);

            const unsigned short* Ab =
                &xlds[(th * 2 + buf) * XBUF] + c * XROW + q * 8;
            short8 a[16];
#pragma unroll
            for (int k = 0; k < 16; ++k)
                a[k] = *(const short8*)(Ab + k * 32);

            f32x4 ac0 = {0.f, 0.f, 0.f, 0.f};
            f32x4 ac1 = {0.f, 0.f, 0.f, 0.f};
#pragma unroll
            for (int k = 0; k < 16; k += 2) {
                ac0 = __builtin_amdgcn_mfma_f32_16x16x32_bf16(a[k],     wg[k],     ac0, 0, 0, 0);
                ac1 = __builtin_amdgcn_mfma_f32_16x16x32_bf16(a[k + 1], wg[k + 1], ac1, 0, 0, 0);
            }
            f32x4 ac = ac0 + ac1;
            *(f32x4*)(&exch[buf][th][lane][role * 4]) = ac;

            __syncthreads();                               // B1..B16
        }

        __syncthreads();                                   // B17

        // ---- serial combine: 32-step FMA chain over chunk summaries ----
        if (wv == 0 && lane < 16) {
            float As[32], Ms[32];
#pragma unroll
            for (int n = 0; n < 32; ++n) {
                As[n] = summ[n][lane][0];
                Ms[n] = summ[n][lane][1];
            }
            float cr = 0.0f;
#pragma unroll
            for (int n = 0; n < 32; ++n) {
                entry[n][lane] = cr;
                cr = As[n] + Ms[n] * cr;
            }
        }
        __syncthreads();                                   // B18
        __syncthreads();                                   // B19

        if (wv == 0 && lane < 16)
            out[(size_t)b * HH + hgrp * 16 + lane] =
                fmaxf(rmax[0][lane], rmax[1][lane]);
    } else {
        // ========================= SCAN WAVE =========================
        const float b0 = bias[h];
        const float b1 = bias[HH + h];
        const float b2 = bias[2 * HH + h];

        float pOA[16][4], pOM[16][4];   // per-t deferred pairs (static idx)
        float vmax = -1e30f;

        // local tail for chunk ct (raw in exch slot sb): act + local scan
        // (entry=0) + pairs + summary. ct is compile-time after unroll.
        auto tailwork = [&](int ct, int sb) {
            const float* e = &exch[sb][th][lane][0];
            f32x4 az = *(const f32x4*)(e);
            f32x4 af = *(const f32x4*)(e + 4);
            f32x4 ao = *(const f32x4*)(e + 8);

            float aa[4], mm[4], oo[4];
#pragma unroll
            for (int r = 0; r < 4; ++r) {
                float zz = az[r] + b0;
                float ff = af[r] + b1;
                float ov = ao[r] + b2;
                float e2 = fast_exp(2.0f * zz);
                float z  = 1.0f - 2.0f * fast_rcp(e2 + 1.0f);  // tanh
                float f  = fast_rcp(1.0f + fast_exp(-ff));     // sigmoid
                float o  = fast_rcp(1.0f + fast_exp(-ov));     // sigmoid
                aa[r] = f * z;
                mm[r] = 1.0f - f;
                oo[r] = o;
            }

            // in-lane composition of 4 steps
            float A = aa[0], M = mm[0];
#pragma unroll
            for (int r = 1; r < 4; ++r) { A = aa[r] + mm[r] * A; M = mm[r] * M; }

            // inclusive cross-quad scan (verified shuffle pattern)
            float Ap = __shfl_up(A, 16, 64), Mp = __shfl_up(M, 16, 64);
            if (q >= 1) { A = A + M * Ap; M = M * Mp; }
            Ap = __shfl_up(A, 32, 64); Mp = __shfl_up(M, 32, 64);
            if (q >= 2) { A = A + M * Ap; M = M * Mp; }
            // exclusive entry for own quad
            float Ae = __shfl_up(A, 16, 64), Me = __shfl_up(M, 16, 64);
            if (q == 0) { Ae = 0.0f; Me = 1.0f; }

            // per-t local (A_t, M_t) with entry=0; store o-scaled pairs
            float cc = Ae, MM = Me;
#pragma unroll
            for (int r = 0; r < 4; ++r) {
                cc = aa[r] + mm[r] * cc;
                MM = mm[r] * MM;
                pOA[ct][r] = oo[r] * cc;
                pOM[ct][r] = oo[r] * MM;
            }

            // chunk summary from q=3 lanes (full inclusive composition)
            if (lane >= 48) {
                summ[th * 16 + ct][c][0] = A;
                summ[th * 16 + ct][c][1] = M;
            }
        };

        stage(0, 0);
        __syncthreads();                                   // B0

#pragma unroll
        for (int ch = 0; ch < 16; ++ch) {
            const int buf = ch & 1;
            if (ch < 15) stage(ch + 1, buf ^ 1);
            if (ch > 0) tailwork(ch - 1, buf ^ 1);         // slot (ch-1)&1
            __syncthreads();                               // B1..B16
        }
        tailwork(15, 1);

        __syncthreads();                                   // B17
        __syncthreads();                                   // B18

        // ---- apply entries to deferred pairs; reduce ----
#pragma unroll
        for (int n = 0; n < 16; ++n) {
            float ec = entry[th * 16 + n][c];
#pragma unroll
            for (int r = 0; r < 4; ++r)
                vmax = fmaxf(vmax, pOA[n][r] + pOM[n][r] * ec);
        }
        vmax = fmaxf(vmax, __shfl_xor(vmax, 16, 64));
        vmax = fmaxf(vmax, __shfl_xor(vmax, 32, 64));
        if (q == 0) rmax[th][c] = vmax;

        __syncthreads();                                   // B19
    }
}

// ---------------------------------------------------------------------------
extern "C" void kernel_launch(void* const* d_in, const int* in_sizes, int n_in,
                              void* d_out, int out_size, void* d_ws, size_t ws_size,
                              hipStream_t stream) {
    const float* sent = (const float*)d_in[0];
    // d_in[1] = lengths (unused by the math)
    const float* W    = (const float*)d_in[2];
    const float* bias = (const float*)d_in[3];
    float* out        = (float*)d_out;

    const int nX = TT * BB * EE;        // 8,388,608
    unsigned short* Xb = (unsigned short*)d_ws;
    unsigned short* Wb = Xb + nX;       // 16 MiB offset, 16B-aligned

    // X: 2048 blocks, W: 768 blocks (4096 elems each, exact cover)
    convert_inputs<<<2816, 256, 0, stream>>>(sent, W, Xb, Wb);

    dim3 grid(4096);                    // 8 xcd x 4 b x 128 hgrp (16 h each)
    qrnn_fused<<<grid, 512, 0, stream>>>(Xb, Wb, bias, out);
}

// Round 13
// 238.050 us; speedup vs baseline: 1.5738x; 1.5738x over previous
//
#include <hip/hip_runtime.h>
#include <stdint.h>

#define TT 512
#define BB 32
#define EE 512
#define HH 2048

typedef __attribute__((ext_vector_type(8))) short short8;   // 8 x bf16 (4 VGPRs)
typedef __attribute__((ext_vector_type(4))) float f32x4;    // MFMA accumulator

// LDS geometry (in shorts)
#define XROW 528            // 512 data + 16 pad: measured 0 bank conflicts;
                            // 520 gave 8.4M conflicts. Row stride 1056 B.
#define XBUF (16 * XROW)    // one 16-t chunk buffer = 8448 shorts (16.5 KB)

static __device__ __forceinline__ float fast_exp(float x) {
    return __builtin_amdgcn_exp2f(x * 1.44269504f);
}
static __device__ __forceinline__ float fast_rcp(float x) {
    return __builtin_amdgcn_rcpf(x);
}

// Packed fp32->bf16 RNE convert: 1 instr per 2 elements.
static __device__ __forceinline__ unsigned cvtpk_bf16(float lo, float hi) {
    unsigned r;
    asm("v_cvt_pk_bf16_f32 %0, %1, %2" : "=v"(r) : "v"(lo), "v"(hi));
    return r;
}

// Async global->LDS DMA, 16 B/lane (wave-uniform LDS base + lane*16).
static __device__ __forceinline__ void load_lds16(const unsigned short* g, unsigned short* l) {
    __builtin_amdgcn_global_load_lds(
        (const __attribute__((address_space(1))) unsigned int*)(uintptr_t)g,
        (__attribute__((address_space(3))) unsigned int*)(uintptr_t)l,
        16, 0, 0);
}

// ---------------------------------------------------------------------------
// Pre-kernel (R9-verified): BW-optimal convert. Block-uniform X/W partition,
// 16 elems/thread, exact cover, max occupancy.
// ---------------------------------------------------------------------------
__launch_bounds__(256, 8)
__global__ void convert_inputs(const float* __restrict__ X,
                               const float* __restrict__ W,
                               unsigned short* __restrict__ Xb,
                               unsigned short* __restrict__ Wb) {
    // X: 8,388,608 elems = 2048 blocks * 4096; W: 3,145,728 = 768 blocks.
    const int bid = blockIdx.x;
    const float* src;
    unsigned short* dst;
    size_t base;
    if (bid < 2048) { src = X; dst = Xb; base = (size_t)bid * 4096; }
    else            { src = W; dst = Wb; base = (size_t)(bid - 2048) * 4096; }
    size_t j = base + (size_t)threadIdx.x * 16;

    float4 v0 = *(const float4*)(src + j);
    float4 v1 = *(const float4*)(src + j + 4);
    float4 v2 = *(const float4*)(src + j + 8);
    float4 v3 = *(const float4*)(src + j + 12);
    union { short8 s; unsigned u[4]; } o0, o1;
    o0.u[0] = cvtpk_bf16(v0.x, v0.y);
    o0.u[1] = cvtpk_bf16(v0.z, v0.w);
    o0.u[2] = cvtpk_bf16(v1.x, v1.y);
    o0.u[3] = cvtpk_bf16(v1.z, v1.w);
    o1.u[0] = cvtpk_bf16(v2.x, v2.y);
    o1.u[1] = cvtpk_bf16(v2.z, v2.w);
    o1.u[2] = cvtpk_bf16(v3.x, v3.y);
    o1.u[3] = cvtpk_bf16(v3.z, v3.w);
    *(short8*)(dst + j)     = o0.s;
    *(short8*)(dst + j + 8) = o1.s;
}

// ---------------------------------------------------------------------------
// Fused QRNN kernel — R17: EXACT R9 structure (session best, 171.6 us) with
// the tail role ROTATED by block parity.
//
// R12 post-mortem: hierarchical scan regressed on residency (1 block/CU).
// 11 structural probes bracket the plateau at 172-179 us whenever >=2
// blocks/CU and no extra work. Final low-risk delta: in R9 the ~800-cyc
// serial tail always runs on s=0 waves -> SIMDs 0,2 of every block; both
// co-resident blocks contend for the same two SIMDs while 1,3 idle at the
// barrier. stail = slot&1 puts tails of opposite-parity blocks on disjoint
// SIMD sets {0,2} vs {1,3}. Instruction counts, barriers, hazards: identical
// to R9; only the wave->role mapping flips per block.
//
// R9-verified structure: K-split 2-way, 4 waves, W pinned in AGPR, X staged
// by global_load_lds DMA (double-buffered, XROW=528), rotated software
// pipeline (region ch issues MFMA(ch), runs tail(ch-1)), early exch read,
// XCD-aware block swizzle, setprio(1) around the MFMA burst, ONE
// __syncthreads per chunk.
// Hazards: (1) publish(ch) vs tail-read(ch): barrier(ch). (2) tail-read(ch)
// vs re-publish(ch+2): barrier(ch+1). (3) X buf reread/rewrite: lgkm drained
// at barrier. (4) stage(ch+1) DMA vs consume in ch+1: vmcnt drained at
// barrier(ch). (5) Barriers wave-uniform; role conditionals contain none.
// ---------------------------------------------------------------------------
__launch_bounds__(256, 2)
__global__ void qrnn_fused(const unsigned short* __restrict__ Xb, // bf16 (T,B,E)
                           const unsigned short* __restrict__ Wb, // bf16 (3H,E)
                           const float* __restrict__ bias,        // (3H)
                           float* __restrict__ out)               // (B,H) fp32
{
    __shared__ unsigned short xlds[2 * XBUF];      // 33,792 B
    __shared__ float exch[2][2][64][12];           // 12,288 B  (total 46,080 B)

    const int tid  = threadIdx.x;
    const int wv   = tid >> 6;         // wave 0..3
    const int lane = tid & 63;
    const int q    = lane >> 4;        // quad 0..3
    const int c    = lane & 15;        // column within 16x16 tile
    const int hi   = wv >> 1;          // h-tile 0..1
    const int s    = wv & 1;           // k-half 0..1

    // XCD-aware swizzle: 2048 blocks = 8 XCDs x 4 batches x 64 h-groups.
    const int id   = blockIdx.x;       // 0..2047
    const int xcd  = id & 7;
    const int slot = id >> 3;          // 0..255 within this XCD
    const int b    = xcd * 4 + (slot >> 6);   // 4 batches per XCD
    const int hgrp = slot & 63;               // 64 h-groups per batch
    const int h    = hgrp * 32 + hi * 16 + c;

    // Tail-role rotation: opposite-parity blocks put tails on disjoint SIMD
    // sets ({0,2} vs {1,3}) -> co-resident tail contention halves (expected).
    const int stail = slot & 1;        // k-half that runs the tail
    const int spub  = stail ^ 1;       // k-half that publishes partials

    // ---- preload W fragments (this wave's K half); pin into AGPRs ----
    // B-frag layout for 16x16x32: lane holds n = lane&15 (= h), k = q*8 + j.
    short8 wz[8], wf[8], wo[8];
    {
        const unsigned short* wzr = Wb + (size_t)h * EE            + s * 256;
        const unsigned short* wfr = Wb + (size_t)(HH + h) * EE     + s * 256;
        const unsigned short* wor = Wb + (size_t)(2 * HH + h) * EE + s * 256;
#pragma unroll
        for (int k = 0; k < 8; ++k) {
            int e0 = k * 32 + q * 8;
            wz[k] = *(const short8*)(wzr + e0);
            wf[k] = *(const short8*)(wfr + e0);
            wo[k] = *(const short8*)(wor + e0);
        }
    }
#pragma unroll
    for (int k = 0; k < 8; ++k) {
        asm volatile("" : "+a"(wz[k]), "+a"(wf[k]), "+a"(wo[k]));
    }

    // Bias enters once via the TAIL wave's accumulator init.
    const float b0 = (s == stail) ? bias[h]          : 0.0f;
    const float b1 = (s == stail) ? bias[HH + h]     : 0.0f;
    const float b2 = (s == stail) ? bias[2 * HH + h] : 0.0f;

    float carry = 0.0f;
    float vmax  = -1e30f;

    // ---- staging: wave wv owns rows wv*4 .. wv*4+3 of each 16-t chunk ----
    const unsigned short* g0 = Xb + ((size_t)(wv * 4) * BB + b) * EE + lane * 8;
    unsigned short* l0 = &xlds[(wv * 4) * XROW];

    auto stage = [&](int n, int slt) {
        const unsigned short* g = g0 + (size_t)n * (16 * BB * EE);
        unsigned short* l = l0 + slt * XBUF;
#pragma unroll
        for (int i = 0; i < 4; ++i)
            load_lds16(g + (size_t)i * (BB * EE), l + i * XROW);
    };

    // tail for one chunk's fully-summed accumulators (tail wave only).
    auto do_tail = [&](f32x4 az, f32x4 af, f32x4 ao) {
        float aa[4], mm[4], oo[4];
#pragma unroll
        for (int r = 0; r < 4; ++r) {
            float e2 = fast_exp(2.0f * az[r]);
            float z  = 1.0f - 2.0f * fast_rcp(e2 + 1.0f);  // tanh
            float f  = fast_rcp(1.0f + fast_exp(-af[r]));  // sigmoid
            float o  = fast_rcp(1.0f + fast_exp(-ao[r]));  // sigmoid
            aa[r] = f * z;
            mm[r] = 1.0f - f;
            oo[r] = o;
        }

        float A = aa[0], M = mm[0];
#pragma unroll
        for (int r = 1; r < 4; ++r) { A = aa[r] + mm[r] * A; M = mm[r] * M; }

        float Ap = __shfl_up(A, 16, 64), Mp = __shfl_up(M, 16, 64);
        if (q >= 1) { A = A + M * Ap; M = M * Mp; }
        Ap = __shfl_up(A, 32, 64); Mp = __shfl_up(M, 32, 64);
        if (q >= 2) { A = A + M * Ap; M = M * Mp; }
        float Ae = __shfl_up(A, 16, 64), Me = __shfl_up(M, 16, 64);
        if (q == 0) { Ae = 0.0f; Me = 1.0f; }
        float cc = Ae + Me * carry;

#pragma unroll
        for (int r = 0; r < 4; ++r) {
            cc = aa[r] + mm[r] * cc;
            vmax = fmaxf(vmax, oo[r] * cc);
        }

        float cend = A + M * carry;
        carry = __shfl(cend, 48 + c, 64);
    };

    stage(0, 0);
    __syncthreads();

    f32x4 prevz, prevf, prevo;   // MFMA results of chunk ch-1 (rotation state)

    for (int ch = 0; ch < 32; ++ch) {
        const int buf = ch & 1;
        if (ch < 31) stage(ch + 1, buf ^ 1);

        // ---- prefetch ALL A-frags for this chunk (8 back-to-back b128) ----
        const unsigned short* Abase = &xlds[buf * XBUF + c * XROW + s * 256 + q * 8];
        short8 a[8];
#pragma unroll
        for (int k = 0; k < 8; ++k)
            a[k] = *(const short8*)(Abase + k * 32);

        // ---- early exchange read for tail(ch-1) ----
        f32x4 pz, pf, po;
        if (s == stail && ch > 0) {
            const float* e = &exch[(ch - 1) & 1][hi][lane][0];
            pz = *(const f32x4*)(e);
            pf = *(const f32x4*)(e + 4);
            po = *(const f32x4*)(e + 8);
        }

        // ---- MFMA burst: 24 MFMAs, 3 independent chains; setprio(1) ----
        f32x4 az = {b0, b0, b0, b0};
        f32x4 af = {b1, b1, b1, b1};
        f32x4 ao = {b2, b2, b2, b2};
        __builtin_amdgcn_s_setprio(1);
#pragma unroll
        for (int k = 0; k < 8; ++k) {
            az = __builtin_amdgcn_mfma_f32_16x16x32_bf16(a[k], wz[k], az, 0, 0, 0);
            af = __builtin_amdgcn_mfma_f32_16x16x32_bf16(a[k], wf[k], af, 0, 0, 0);
            ao = __builtin_amdgcn_mfma_f32_16x16x32_bf16(a[k], wo[k], ao, 0, 0, 0);
        }
        __builtin_amdgcn_s_setprio(0);

        // ---- publisher wave writes THIS chunk's partials ----
        if (s == spub) {
            float* e = &exch[ch & 1][hi][lane][0];
            *(f32x4*)(e)     = az;
            *(f32x4*)(e + 4) = af;
            *(f32x4*)(e + 8) = ao;
        }

        // ---- tail(ch-1): pure VALU on prev* + p*; overlaps matrix pipe ----
        if (s == stail && ch > 0) {
            do_tail(prevz + pz, prevf + pf, prevo + po);
        }

        prevz = az; prevf = af; prevo = ao;

        __syncthreads();   // the ONE barrier per chunk (hazards 1-4)
    }

    // ---- epilogue: tail(31) ----
    if (s == stail) {
        const float* e = &exch[31 & 1][hi][lane][0];
        f32x4 pz = *(const f32x4*)(e);
        f32x4 pf = *(const f32x4*)(e + 4);
        f32x4 po = *(const f32x4*)(e + 8);
        do_tail(prevz + pz, prevf + pf, prevo + po);

        vmax = fmaxf(vmax, __shfl_xor(vmax, 16, 64));
        vmax = fmaxf(vmax, __shfl_xor(vmax, 32, 64));
        if (q == 0) out[(size_t)b * HH + h] = vmax;
    }
}

// ---------------------------------------------------------------------------
extern "C" void kernel_launch(void* const* d_in, const int* in_sizes, int n_in,
                              void* d_out, int out_size, void* d_ws, size_t ws_size,
                              hipStream_t stream) {
    const float* sent = (const float*)d_in[0];
    // d_in[1] = lengths (unused by the math)
    const float* W    = (const float*)d_in[2];
    const float* bias = (const float*)d_in[3];
    float* out        = (float*)d_out;

    const int nX = TT * BB * EE;        // 8,388,608
    unsigned short* Xb = (unsigned short*)d_ws;
    unsigned short* Wb = Xb + nX;       // 16 MiB offset, 16B-aligned

    // X: 2048 blocks, W: 768 blocks (4096 elems each, exact cover)
    convert_inputs<<<2816, 256, 0, stream>>>(sent, W, Xb, Wb);

    dim3 grid(2048);                    // 1-D: swizzled to (xcd, b, hgrp) in-kernel
    qrnn_fused<<<grid, 256, 0, stream>>>(Xb, Wb, bias, out);
}